// Round 1
// baseline (188.825 us; speedup 1.0000x reference)
//
#include <hip/hip_runtime.h>

#define PHH 7
#define PWW 7
static constexpr float SPATIAL_SCALE = 0.0625f;

// Antiderivative of hat function phi(t) = max(0, 1-|t|), saturating to [0,1].
__device__ __forceinline__ float hat_int(float t) {
    t = fminf(fmaxf(t, -1.0f), 1.0f);
    float a = t + 1.0f, b = 1.0f - t;
    return (t <= 0.0f) ? 0.5f * a * a : 1.0f - 0.5f * b * b;
}

// Exact 1D integral of the hat basis at grid node g over [lo, hi].
__device__ __forceinline__ float bin_w(float lo, float hi, float g) {
    return hat_int(hi - g) - hat_int(lo - g);
}

// NCHW -> NHWC transpose (per n: [C, HW] -> [HW, C]), 32x32 LDS tiles.
__global__ __launch_bounds__(256) void transpose_nchw_nhwc(
    const float* __restrict__ src, float* __restrict__ dst, int C, int HW)
{
    __shared__ float tile[32][33];
    const int n = blockIdx.z;
    const int hw0 = blockIdx.x * 32;
    const int c0 = blockIdx.y * 32;
    const float* s = src + (size_t)n * C * HW;
    float* d = dst + (size_t)n * C * HW;
    const int tx = threadIdx.x, ty = threadIdx.y;
    #pragma unroll
    for (int i = ty; i < 32; i += 8) {
        int c = c0 + i, hw = hw0 + tx;
        if (c < C && hw < HW) tile[i][tx] = s[(size_t)c * HW + hw];
    }
    __syncthreads();
    #pragma unroll
    for (int i = ty; i < 32; i += 8) {
        int hw = hw0 + i, c = c0 + tx;
        if (c < C && hw < HW) d[(size_t)hw * C + c] = tile[tx][i];
    }
}

// One block per (roi, p). Threads = channels (coalesced along C in NHWC).
__global__ __launch_bounds__(256) void prroi_pool_nhwc(
    const float* __restrict__ ft,    // [N, H, W, C]
    const float* __restrict__ rois,  // [R, 5]
    float* __restrict__ out,         // [R, C, PHH, PWW]
    int C, int H, int W)
{
    const int r = blockIdx.x / PHH;
    const int p = blockIdx.x % PHH;
    const float* roi = rois + (size_t)r * 5;
    const int b = (int)roi[0];
    const float x1 = roi[1] * SPATIAL_SCALE;
    const float y1 = roi[2] * SPATIAL_SCALE;
    const float x2 = roi[3] * SPATIAL_SCALE;
    const float y2 = roi[4] * SPATIAL_SCALE;
    const float rw = fmaxf(x2 - x1, 0.0f);
    const float rh = fmaxf(y2 - y1, 0.0f);
    const float bw = rw / (float)PWW;
    const float bh = rh / (float)PHH;
    const float area = bw * bh;
    const float inv_area = (area > 0.0f) ? 1.0f / fmaxf(area, 1e-12f) : 0.0f;

    const float ylo = y1 + (float)p * bh;
    const float yhi = ylo + bh;
    const int h0 = max(0, (int)ceilf(ylo - 1.0f));
    const int h1 = min(H - 1, (int)floorf(yhi + 1.0f));
    const int w0 = max(0, (int)ceilf(x1 - 1.0f));
    const int w1 = min(W - 1, (int)floorf(x2 + 1.0f));
    const int ww = w1 - w0 + 1;  // <= W (152)

    __shared__ float wxs[PWW][152];
    if (ww > 0) {
        for (int i = threadIdx.x; i < PWW * ww; i += blockDim.x) {
            int q = i / ww, wi = i - q * ww;
            float xlo = x1 + (float)q * bw;
            wxs[q][wi] = bin_w(xlo, xlo + bw, (float)(w0 + wi));
        }
    }
    __syncthreads();

    for (int c = threadIdx.x; c < C; c += blockDim.x) {
        float acc[PWW] = {0.f, 0.f, 0.f, 0.f, 0.f, 0.f, 0.f};
        for (int h = h0; h <= h1; ++h) {
            const float wy = bin_w(ylo, yhi, (float)h);
            const float* fr = ft + (((size_t)b * H + h) * W + w0) * C + c;
            for (int wi = 0; wi < ww; ++wi) {
                float t = wy * fr[(size_t)wi * C];
                #pragma unroll
                for (int q = 0; q < PWW; ++q)
                    acc[q] = fmaf(wxs[q][wi], t, acc[q]);
            }
        }
        float* o = out + (((size_t)r * C + c) * PHH + p) * PWW;
        #pragma unroll
        for (int q = 0; q < PWW; ++q)
            o[q] = acc[q] * inv_area;
    }
}

// Fallback (no scratch): one thread per output element, reads NCHW directly.
__global__ __launch_bounds__(256) void prroi_pool_nchw(
    const float* __restrict__ f, const float* __restrict__ rois,
    float* __restrict__ out, int C, int H, int W, int R)
{
    const int idx = blockIdx.x * blockDim.x + threadIdx.x;
    const int total = R * C * PHH * PWW;
    if (idx >= total) return;
    const int q = idx % PWW;
    const int p = (idx / PWW) % PHH;
    const int c = (idx / (PWW * PHH)) % C;
    const int r = idx / (PWW * PHH * C);
    const float* roi = rois + (size_t)r * 5;
    const int b = (int)roi[0];
    const float x1 = roi[1] * SPATIAL_SCALE;
    const float y1 = roi[2] * SPATIAL_SCALE;
    const float x2 = roi[3] * SPATIAL_SCALE;
    const float y2 = roi[4] * SPATIAL_SCALE;
    const float bw = fmaxf(x2 - x1, 0.0f) / (float)PWW;
    const float bh = fmaxf(y2 - y1, 0.0f) / (float)PHH;
    const float area = bw * bh;
    const float inv_area = (area > 0.0f) ? 1.0f / fmaxf(area, 1e-12f) : 0.0f;
    const float xlo = x1 + (float)q * bw, xhi = xlo + bw;
    const float ylo = y1 + (float)p * bh, yhi = ylo + bh;
    const int h0 = max(0, (int)ceilf(ylo - 1.0f));
    const int h1 = min(H - 1, (int)floorf(yhi + 1.0f));
    const int w0 = max(0, (int)ceilf(xlo - 1.0f));
    const int w1 = min(W - 1, (int)floorf(xhi + 1.0f));
    float acc = 0.0f;
    for (int h = h0; h <= h1; ++h) {
        const float wy = bin_w(ylo, yhi, (float)h);
        const float* fr = f + (((size_t)b * C + c) * H + h) * W;
        for (int w = w0; w <= w1; ++w)
            acc = fmaf(wy * bin_w(xlo, xhi, (float)w), fr[w], acc);
    }
    out[idx] = acc * inv_area;
}

extern "C" void kernel_launch(void* const* d_in, const int* in_sizes, int n_in,
                              void* d_out, int out_size, void* d_ws, size_t ws_size,
                              hipStream_t stream)
{
    const float* features = (const float*)d_in[0];
    const float* rois = (const float*)d_in[1];
    float* out = (float*)d_out;

    const int C = 256, H = 152, W = 152;
    const int N = in_sizes[0] / (C * H * W);
    const int R = in_sizes[1] / 5;

    const size_t need = (size_t)N * C * H * W * sizeof(float);
    if (ws_size >= need) {
        float* ft = (float*)d_ws;
        const int HW = H * W;
        dim3 tgrid((HW + 31) / 32, (C + 31) / 32, N);
        transpose_nchw_nhwc<<<tgrid, dim3(32, 8), 0, stream>>>(features, ft, C, HW);
        prroi_pool_nhwc<<<R * PHH, 256, 0, stream>>>(ft, rois, out, C, H, W);
    } else {
        const int total = R * C * PHH * PWW;
        prroi_pool_nchw<<<(total + 255) / 256, 256, 0, stream>>>(features, rois, out, C, H, W, R);
    }
}

// Round 2
// 107.143 us; speedup vs baseline: 1.7624x; 1.7624x over previous
//
#include <hip/hip_runtime.h>

#define PHH 7
#define PWW 7
static constexpr float SPATIAL_SCALE = 0.0625f;

// Antiderivative of hat function phi(t) = max(0, 1-|t|), saturating to [0,1].
__device__ __forceinline__ float hat_int(float t) {
    t = fminf(fmaxf(t, -1.0f), 1.0f);
    float a = t + 1.0f, b = 1.0f - t;
    return (t <= 0.0f) ? 0.5f * a * a : 1.0f - 0.5f * b * b;
}

// Exact 1D integral of the hat basis at grid node g over [lo, hi].
__device__ __forceinline__ float bin_w(float lo, float hi, float g) {
    return hat_int(hi - g) - hat_int(lo - g);
}

// NCHW -> NHWC transpose (per n: [C, HW] -> [HW, C]), 32x32 LDS tiles.
// 94 MB HBM traffic @ ~6.3 TB/s -> ~15 us (at ceiling, measured r1).
__global__ __launch_bounds__(256) void transpose_nchw_nhwc(
    const float* __restrict__ src, float* __restrict__ dst, int C, int HW)
{
    __shared__ float tile[32][33];
    const int n = blockIdx.z;
    const int hw0 = blockIdx.x * 32;
    const int c0 = blockIdx.y * 32;
    const float* s = src + (size_t)n * C * HW;
    float* d = dst + (size_t)n * C * HW;
    const int tx = threadIdx.x, ty = threadIdx.y;
    #pragma unroll
    for (int i = ty; i < 32; i += 8) {
        int c = c0 + i, hw = hw0 + tx;
        if (c < C && hw < HW) tile[i][tx] = s[(size_t)c * HW + hw];
    }
    __syncthreads();
    #pragma unroll
    for (int i = ty; i < 32; i += 8) {
        int hw = hw0 + i, c = c0 + tx;
        if (c < C && hw < HW) d[(size_t)hw * C + c] = tile[tx][i];
    }
}

// One block per (roi, p). 64 lanes x 4 channels = C=256 (float4 loads);
// the 4 waves split the wi columns 4-way; LDS tree-reduce at the end.
// Inner loop is h-factorized: s = sum_h wy*f (2 FLOP/elem), then 7 q-FMAs/wi.
__global__ __launch_bounds__(256) void prroi_pool_nhwc(
    const float* __restrict__ ft,    // [N, H, W, C]
    const float* __restrict__ rois,  // [R, 5]
    float* __restrict__ out,         // [R, C, PHH, PWW]
    int C, int H, int W)
{
    const int r = blockIdx.x / PHH;
    const int p = blockIdx.x % PHH;
    const float* roi = rois + (size_t)r * 5;
    const int b = (int)roi[0];
    const float x1 = roi[1] * SPATIAL_SCALE;
    const float y1 = roi[2] * SPATIAL_SCALE;
    const float x2 = roi[3] * SPATIAL_SCALE;
    const float y2 = roi[4] * SPATIAL_SCALE;
    const float bw = fmaxf(x2 - x1, 0.0f) / (float)PWW;
    const float bh = fmaxf(y2 - y1, 0.0f) / (float)PHH;
    const float area = bw * bh;
    const float inv_area = (area > 0.0f) ? 1.0f / fmaxf(area, 1e-12f) : 0.0f;

    const float ylo = y1 + (float)p * bh;
    const float yhi = ylo + bh;
    const int h0 = max(0, (int)ceilf(ylo - 1.0f));
    const int h1 = min(H - 1, (int)floorf(yhi + 1.0f));
    const int w0 = max(0, (int)ceilf(x1 - 1.0f));
    const int w1 = min(W - 1, (int)floorf(x2 + 1.0f));
    const int ww = w1 - w0 + 1;   // <= W (152)
    const int nh = h1 - h0 + 1;   // <= H (152)

    __shared__ float wxs[PWW][152];
    __shared__ float wys[152];
    __shared__ float rbuf[3][64][PWW * 4];  // 21.5 KB cross-wave reduce

    for (int i = threadIdx.x; i < nh; i += 256)
        wys[i] = bin_w(ylo, yhi, (float)(h0 + i));
    if (ww > 0) {
        for (int i = threadIdx.x; i < PWW * ww; i += 256) {
            int q = i / ww, wi = i - q * ww;
            float xlo = x1 + (float)q * bw;
            wxs[q][wi] = bin_w(xlo, xlo + bw, (float)(w0 + wi));
        }
    }
    __syncthreads();

    const int lane = threadIdx.x & 63;
    const int wig = threadIdx.x >> 6;
    const int c0 = lane * 4;

    float acc[PWW][4];
    #pragma unroll
    for (int q = 0; q < PWW; ++q)
        #pragma unroll
        for (int k = 0; k < 4; ++k) acc[q][k] = 0.0f;

    if (ww > 0 && nh > 0) {
        const size_t rowstride = (size_t)W * C;
        for (int wi = wig; wi < ww; wi += 4) {
            const float* fp = ft + (((size_t)b * H + h0) * W + (w0 + wi)) * C + c0;
            float s0 = 0.f, s1 = 0.f, s2 = 0.f, s3 = 0.f;
            for (int i = 0; i < nh; ++i) {
                const float wy = wys[i];
                const float4 f = *(const float4*)fp;
                s0 = fmaf(wy, f.x, s0);
                s1 = fmaf(wy, f.y, s1);
                s2 = fmaf(wy, f.z, s2);
                s3 = fmaf(wy, f.w, s3);
                fp += rowstride;
            }
            #pragma unroll
            for (int q = 0; q < PWW; ++q) {
                const float wq = wxs[q][wi];
                acc[q][0] = fmaf(wq, s0, acc[q][0]);
                acc[q][1] = fmaf(wq, s1, acc[q][1]);
                acc[q][2] = fmaf(wq, s2, acc[q][2]);
                acc[q][3] = fmaf(wq, s3, acc[q][3]);
            }
        }
    }

    if (wig > 0) {
        #pragma unroll
        for (int q = 0; q < PWW; ++q)
            #pragma unroll
            for (int k = 0; k < 4; ++k)
                rbuf[wig - 1][lane][q * 4 + k] = acc[q][k];
    }
    __syncthreads();
    if (wig == 0) {
        #pragma unroll
        for (int g = 0; g < 3; ++g)
            #pragma unroll
            for (int q = 0; q < PWW; ++q)
                #pragma unroll
                for (int k = 0; k < 4; ++k)
                    acc[q][k] += rbuf[g][lane][q * 4 + k];
        float* o = out + ((size_t)r * C + c0) * (PHH * PWW) + p * PWW;
        #pragma unroll
        for (int k = 0; k < 4; ++k)
            #pragma unroll
            for (int q = 0; q < PWW; ++q)
                o[(size_t)k * (PHH * PWW) + q] = acc[q][k] * inv_area;
    }
}

// Fallback (no scratch): one thread per output element, reads NCHW directly.
__global__ __launch_bounds__(256) void prroi_pool_nchw(
    const float* __restrict__ f, const float* __restrict__ rois,
    float* __restrict__ out, int C, int H, int W, int R)
{
    const int idx = blockIdx.x * blockDim.x + threadIdx.x;
    const int total = R * C * PHH * PWW;
    if (idx >= total) return;
    const int q = idx % PWW;
    const int p = (idx / PWW) % PHH;
    const int c = (idx / (PWW * PHH)) % C;
    const int r = idx / (PWW * PHH * C);
    const float* roi = rois + (size_t)r * 5;
    const int b = (int)roi[0];
    const float x1 = roi[1] * SPATIAL_SCALE;
    const float y1 = roi[2] * SPATIAL_SCALE;
    const float x2 = roi[3] * SPATIAL_SCALE;
    const float y2 = roi[4] * SPATIAL_SCALE;
    const float bw = fmaxf(x2 - x1, 0.0f) / (float)PWW;
    const float bh = fmaxf(y2 - y1, 0.0f) / (float)PHH;
    const float area = bw * bh;
    const float inv_area = (area > 0.0f) ? 1.0f / fmaxf(area, 1e-12f) : 0.0f;
    const float xlo = x1 + (float)q * bw, xhi = xlo + bw;
    const float ylo = y1 + (float)p * bh, yhi = ylo + bh;
    const int h0 = max(0, (int)ceilf(ylo - 1.0f));
    const int h1 = min(H - 1, (int)floorf(yhi + 1.0f));
    const int w0 = max(0, (int)ceilf(xlo - 1.0f));
    const int w1 = min(W - 1, (int)floorf(xhi + 1.0f));
    float acc = 0.0f;
    for (int h = h0; h <= h1; ++h) {
        const float wy = bin_w(ylo, yhi, (float)h);
        const float* fr = f + (((size_t)b * C + c) * H + h) * W;
        for (int w = w0; w <= w1; ++w)
            acc = fmaf(wy * bin_w(xlo, xhi, (float)w), fr[w], acc);
    }
    out[idx] = acc * inv_area;
}

extern "C" void kernel_launch(void* const* d_in, const int* in_sizes, int n_in,
                              void* d_out, int out_size, void* d_ws, size_t ws_size,
                              hipStream_t stream)
{
    const float* features = (const float*)d_in[0];
    const float* rois = (const float*)d_in[1];
    float* out = (float*)d_out;

    const int C = 256, H = 152, W = 152;
    const int N = in_sizes[0] / (C * H * W);
    const int R = in_sizes[1] / 5;

    const size_t need = (size_t)N * C * H * W * sizeof(float);
    if (ws_size >= need && C == 256) {
        float* ft = (float*)d_ws;
        const int HW = H * W;
        dim3 tgrid((HW + 31) / 32, (C + 31) / 32, N);
        transpose_nchw_nhwc<<<tgrid, dim3(32, 8), 0, stream>>>(features, ft, C, HW);
        prroi_pool_nhwc<<<R * PHH, 256, 0, stream>>>(ft, rois, out, C, H, W);
    } else {
        const int total = R * C * PHH * PWW;
        prroi_pool_nchw<<<(total + 255) / 256, 256, 0, stream>>>(features, rois, out, C, H, W, R);
    }
}